// Round 1
// baseline (423.163 us; speedup 1.0000x reference)
//
#include <hip/hip_runtime.h>
#include <stdint.h>

// ---------- types ----------
typedef __bf16 bf16x8 __attribute__((ext_vector_type(8)));
typedef float  f32x4  __attribute__((ext_vector_type(4)));

union U16x8 { uint4 u; uint16_t s[8]; };

__device__ __forceinline__ uint16_t f2b(float f) {
    union { float f; uint32_t u; } c; c.f = f;
    uint32_t u = c.u;
    uint32_t r = u + 0x7fffu + ((u >> 16) & 1u);   // round-to-nearest-even
    return (uint16_t)(r >> 16);
}

__device__ __forceinline__ uint32_t asu(float f) {
    union { float f; uint32_t u; } c; c.f = f; return c.u;
}
// pack two f32 -> two bf16 (half-up rounding), lo = a, hi = b
__device__ __forceinline__ uint32_t pack_bf16_hu(float a, float b) {
    uint32_t ua = asu(a) + 0x8000u, ub = asu(b) + 0x8000u;
    return (ua >> 16) | (ub & 0xffff0000u);        // v_lshr + v_and_or
}

// async global->LDS, 16B per lane; dest must be lane-contiguous
__device__ __forceinline__ void gl_lds16(const uint16_t* g, uint16_t* l) {
    __builtin_amdgcn_global_load_lds(
        (const __attribute__((address_space(1))) void*)g,
        (__attribute__((address_space(3))) void*)l, 16, 0, 0);
}

// ---------- prep kernels ----------
// q,k,v fp32 -> bf16 in one launch (y selects tensor)
__global__ void cast3_f32_bf16(const float* __restrict__ x0, const float* __restrict__ x1,
                               const float* __restrict__ x2,
                               uint16_t* __restrict__ y0, uint16_t* __restrict__ y1,
                               uint16_t* __restrict__ y2, int n4) {
    const float* x; uint16_t* y;
    switch (blockIdx.y) {
        case 0: x = x0; y = y0; break;
        case 1: x = x1; y = y1; break;
        default: x = x2; y = y2; break;
    }
    int i = blockIdx.x * blockDim.x + threadIdx.x;
    if (i < n4) {
        float4 v = ((const float4*)x)[i];
        ushort4 o;
        o.x = f2b(v.x); o.y = f2b(v.y); o.z = f2b(v.z); o.w = f2b(v.w);
        *(ushort4*)(y + (size_t)i * 4) = o;
    }
}

// 4 weights [1024,1024] fp32 [k][n] -> bf16 [n][k], one launch (z selects weight)
__global__ void transpose_cast4(const float* __restrict__ W0, const float* __restrict__ W1,
                                const float* __restrict__ W2, const float* __restrict__ W3,
                                uint16_t* __restrict__ O0, uint16_t* __restrict__ O1,
                                uint16_t* __restrict__ O2, uint16_t* __restrict__ O3) {
    __shared__ float tile[64][65];
    const float* W; uint16_t* Wt;
    switch (blockIdx.z) {
        case 0: W = W0; Wt = O0; break;
        case 1: W = W1; Wt = O1; break;
        case 2: W = W2; Wt = O2; break;
        default: W = W3; Wt = O3; break;
    }
    const int k0 = blockIdx.y * 64, n0 = blockIdx.x * 64;
    const int tx = threadIdx.x & 63, ty = threadIdx.x >> 6;
    #pragma unroll
    for (int r = ty; r < 64; r += 4)
        tile[r][tx] = W[(size_t)(k0 + r) * 1024 + n0 + tx];
    __syncthreads();
    #pragma unroll
    for (int r = ty; r < 64; r += 4)
        Wt[(size_t)(n0 + r) * 1024 + k0 + tx] = f2b(tile[tx][r]);
}

// ---------- fused QKV projection GEMM ----------
// C[8192,1024] = A[M,K](bf16) * Bt[N,K](bf16) + bias, out bf16 head-split [B,H,S,dk]
// blockIdx.z picks (A, Bt, bias, out); z==0 (Q) applies qscale.
__global__ __launch_bounds__(256, 3)
void gemm_qkv(const uint16_t* __restrict__ A0, const uint16_t* __restrict__ A1,
              const uint16_t* __restrict__ A2,
              const uint16_t* __restrict__ B0, const uint16_t* __restrict__ B1,
              const uint16_t* __restrict__ B2,
              const float* __restrict__ c0, const float* __restrict__ c1,
              const float* __restrict__ c2,
              uint16_t* __restrict__ O0, uint16_t* __restrict__ O1,
              uint16_t* __restrict__ O2, float qscale) {
    __shared__ uint16_t SH[2 * 128 * 32] __attribute__((aligned(16)));
    uint16_t* As = SH;
    uint16_t* Bs = SH + 128 * 32;

    const uint16_t* A; const uint16_t* Bt; const float* bias; uint16_t* Cout; float scale;
    switch (blockIdx.z) {
        case 0: A = A0; Bt = B0; bias = c0; Cout = O0; scale = qscale; break;
        case 1: A = A1; Bt = B1; bias = c1; Cout = O1; scale = 1.0f;  break;
        default: A = A2; Bt = B2; bias = c2; Cout = O2; scale = 1.0f; break;
    }

    const int tid = threadIdx.x;
    const int m0 = blockIdx.y * 128, n0 = blockIdx.x * 128;
    const int l = tid & 63, ln = l & 15, qd = l >> 4;
    const int w = tid >> 6;
    const int wm = (w >> 1) * 64, wn = (w & 1) * 64;

    f32x4 acc[4][4] = {};

    for (int kk = 0; kk < 1024; kk += 32) {
        __syncthreads();
        #pragma unroll
        for (int i = 0; i < 2; i++) {
            int c = tid + i * 256;           // 512 chunks of 8 bf16 per tile
            gl_lds16(&A[(size_t)(m0 + (c >> 2)) * 1024 + kk + (c & 3) * 8], &As[c * 8]);
            gl_lds16(&Bt[(size_t)(n0 + (c >> 2)) * 1024 + kk + (c & 3) * 8], &Bs[c * 8]);
        }
        __syncthreads();

        bf16x8 af[4], bfr[4];
        #pragma unroll
        for (int i = 0; i < 4; i++)
            af[i] = *(const bf16x8*)&As[(wm + i * 16 + ln) * 32 + qd * 8];
        #pragma unroll
        for (int j = 0; j < 4; j++)
            bfr[j] = *(const bf16x8*)&Bs[(wn + j * 16 + ln) * 32 + qd * 8];
        #pragma unroll
        for (int i = 0; i < 4; i++)
            #pragma unroll
            for (int j = 0; j < 4; j++)
                acc[i][j] = __builtin_amdgcn_mfma_f32_16x16x32_bf16(af[i], bfr[j], acc[i][j], 0, 0, 0);
    }

    float bv[4];
    #pragma unroll
    for (int j = 0; j < 4; j++) bv[j] = bias[n0 + wn + j * 16 + ln];

    __syncthreads();
    uint16_t* scr = (uint16_t*)SH + w * 1024;      // per-wave 16x64 bf16 patch
    const int colb = n0 + wn;
    const int h = colb >> 6;
    #pragma unroll
    for (int i = 0; i < 4; i++) {
        #pragma unroll
        for (int j = 0; j < 4; j++)
            #pragma unroll
            for (int r = 0; r < 4; r++)
                scr[(qd * 4 + r) * 64 + j * 16 + ln] = f2b((acc[i][j][r] + bv[j]) * scale);
        #pragma unroll
        for (int ii = 0; ii < 2; ii++) {
            int ch = ii * 64 + l, row = ch >> 3, sg = ch & 7;
            int grow = m0 + wm + i * 16 + row;
            int b = grow >> 11, s = grow & 2047;
            *(uint4*)&Cout[(size_t)((b * 16 + h) * 2048 + s) * 64 + sg * 8] =
                *(uint4*)&scr[row * 64 + sg * 8];
        }
    }
}

// ---------- output projection GEMM (fp32 out) ----------
__global__ __launch_bounds__(256, 3)
void gemm_o(const uint16_t* __restrict__ A, const uint16_t* __restrict__ Bt,
            const float* __restrict__ bias, float* __restrict__ Cout) {
    __shared__ uint16_t SH[2 * 128 * 32] __attribute__((aligned(16)));
    uint16_t* As = SH;
    uint16_t* Bs = SH + 128 * 32;

    const int tid = threadIdx.x;
    const int m0 = blockIdx.y * 128, n0 = blockIdx.x * 128;
    const int l = tid & 63, ln = l & 15, qd = l >> 4;
    const int w = tid >> 6;
    const int wm = (w >> 1) * 64, wn = (w & 1) * 64;

    f32x4 acc[4][4] = {};

    for (int kk = 0; kk < 1024; kk += 32) {
        __syncthreads();
        #pragma unroll
        for (int i = 0; i < 2; i++) {
            int c = tid + i * 256;
            gl_lds16(&A[(size_t)(m0 + (c >> 2)) * 1024 + kk + (c & 3) * 8], &As[c * 8]);
            gl_lds16(&Bt[(size_t)(n0 + (c >> 2)) * 1024 + kk + (c & 3) * 8], &Bs[c * 8]);
        }
        __syncthreads();

        bf16x8 af[4], bfr[4];
        #pragma unroll
        for (int i = 0; i < 4; i++)
            af[i] = *(const bf16x8*)&As[(wm + i * 16 + ln) * 32 + qd * 8];
        #pragma unroll
        for (int j = 0; j < 4; j++)
            bfr[j] = *(const bf16x8*)&Bs[(wn + j * 16 + ln) * 32 + qd * 8];
        #pragma unroll
        for (int i = 0; i < 4; i++)
            #pragma unroll
            for (int j = 0; j < 4; j++)
                acc[i][j] = __builtin_amdgcn_mfma_f32_16x16x32_bf16(af[i], bfr[j], acc[i][j], 0, 0, 0);
    }

    float bv[4];
    #pragma unroll
    for (int j = 0; j < 4; j++) bv[j] = bias[n0 + wn + j * 16 + ln];

    __syncthreads();
    float* scr = (float*)SH + w * 1024;            // per-wave 16x64 f32 patch
    #pragma unroll
    for (int i = 0; i < 4; i++) {
        #pragma unroll
        for (int j = 0; j < 4; j++)
            #pragma unroll
            for (int r = 0; r < 4; r++)
                scr[(qd * 4 + r) * 64 + j * 16 + ln] = acc[i][j][r] + bv[j];
        #pragma unroll
        for (int ii = 0; ii < 4; ii++) {
            int ch = ii * 64 + l, row = ch >> 4, sg = ch & 15;
            *(float4*)&Cout[(size_t)(m0 + wm + i * 16 + row) * 1024 + n0 + wn + sg * 4] =
                *(float4*)&scr[row * 64 + sg * 4];
        }
    }
}

// ---------- flash attention (S^T and O^T formulation) ----------
// Qh holds log2e-scaled Q. 512 threads, 256-row Q tile.
// This version: double-buffered K/V staging with ONE barrier per KV tile.
//   K: pre-swizzled global_load_lds into linear [64][64] (chunk c' = c ^ (t&7)),
//      swizzle applied identically on the LDS-read side -> conflict-free b128 reads.
//   V: global loads issued at top of compute (latency hidden under QK^T/softmax),
//      transposed pack written to the *next* buffer late in the iteration.
//   Softmax: defer-max (THR=8 in log2 domain) skips the O-rescale when the
//      running max doesn't grow; s_setprio(1) wraps the MFMA clusters.
__global__ __launch_bounds__(512, 4)
void attn_kernel(const uint16_t* __restrict__ Qh, const uint16_t* __restrict__ Kh,
                 const uint16_t* __restrict__ Vh, uint16_t* __restrict__ Of) {
    __shared__ uint16_t Ks[2][64 * 64] __attribute__((aligned(16)));  // [t][d], XOR-chunk-swizzled
    __shared__ uint16_t Vt[2][64 * 72] __attribute__((aligned(16)));  // [d][t], reg-transposed
    __shared__ uint16_t Ps[256 * 72]   __attribute__((aligned(16)));  // [q][t], per-wave 32 rows

    const int tid = threadIdx.x;
    const int w = tid >> 6, l = tid & 63, ln = l & 15, qd = l >> 4;
    const size_t base = (size_t)blockIdx.y * 131072;
    const int q0 = blockIdx.x * 256;

    // K staging geometry (thread-constant): LDS chunk tid <- global chunk c^(t&7)
    const int krow = tid >> 3;                         // 0..63
    const int kchunk = (tid & 7) ^ (krow & 7);         // swizzled source chunk
    // per-lane swizzled read offsets (halfwords) for the two 32-wide k slices
    const int swz0 = ((0 + qd) ^ (ln & 7)) * 8;
    const int swz1 = ((4 + qd) ^ (ln & 7)) * 8;
    // V staging geometry (valid for w < 4)
    const int vu = tid & 31, vsg = tid >> 5;

    // Q fragments (B-operand): [n=q][k=d]
    bf16x8 qf[2][2];
    #pragma unroll
    for (int tq = 0; tq < 2; tq++)
        #pragma unroll
        for (int ks = 0; ks < 2; ks++)
            qf[tq][ks] = *(const bf16x8*)&Qh[base + (size_t)(q0 + w * 32 + tq * 16 + ln) * 64 + ks * 32 + qd * 8];

    f32x4 oacc[2][4] = {};                          // [tq][dt], O^T: row=d, col=q
    float mrun[2] = { -__builtin_inff(), -__builtin_inff() };
    float lrun[2] = { 0.f, 0.f };

    // ---- prologue: stage tile 0 ----
    gl_lds16(&Kh[base + (size_t)krow * 64 + kchunk * 8], &Ks[0][tid * 8]);
    uint4 vr0, vr1;
    if (w < 4) {
        vr0 = *(const uint4*)&Vh[base + (size_t)(2 * vu) * 64 + vsg * 8];
        vr1 = *(const uint4*)&Vh[base + (size_t)(2 * vu + 1) * 64 + vsg * 8];
        U16x8 a, b; a.u = vr0; b.u = vr1;
        #pragma unroll
        for (int e = 0; e < 8; e++) {
            uint32_t pk = (uint32_t)a.s[e] | ((uint32_t)b.s[e] << 16);
            *(uint32_t*)&Vt[0][(vsg * 8 + e) * 72 + 2 * vu] = pk;
        }
    }

    for (int j = 0; j < 32; j++) {
        const int cur = j & 1, nxt = cur ^ 1;
        __syncthreads();   // publishes K/V of tile j; protects buffers of tile j+1

        // ---- prefetch tile j+1 ----
        if (j < 31) {
            const int t0n = (j + 1) * 64;
            gl_lds16(&Kh[base + (size_t)(t0n + krow) * 64 + kchunk * 8], &Ks[nxt][tid * 8]);
            if (w < 4) {
                vr0 = *(const uint4*)&Vh[base + (size_t)(t0n + 2 * vu) * 64 + vsg * 8];
                vr1 = *(const uint4*)&Vh[base + (size_t)(t0n + 2 * vu + 1) * 64 + vsg * 8];
            }
        }

        // ---- S^T = K Q^T : row=t=(qd*4+r), col=q=ln  (log2 domain) ----
        bf16x8 kb[4][2];
        #pragma unroll
        for (int tt = 0; tt < 4; tt++) {
            kb[tt][0] = *(const bf16x8*)&Ks[cur][(tt * 16 + ln) * 64 + swz0];
            kb[tt][1] = *(const bf16x8*)&Ks[cur][(tt * 16 + ln) * 64 + swz1];
        }
        f32x4 sa[4][2] = {};
        __builtin_amdgcn_s_setprio(1);
        #pragma unroll
        for (int tt = 0; tt < 4; tt++)
            #pragma unroll
            for (int tq = 0; tq < 2; tq++)
                #pragma unroll
                for (int ks = 0; ks < 2; ks++)
                    sa[tt][tq] = __builtin_amdgcn_mfma_f32_16x16x32_bf16(kb[tt][ks], qf[tq][ks], sa[tt][tq], 0, 0, 0);
        __builtin_amdgcn_s_setprio(0);

        // ---- online softmax in log2 domain, defer-max rescale skip ----
        #pragma unroll
        for (int tq = 0; tq < 2; tq++) {
            float mx = -__builtin_inff();
            #pragma unroll
            for (int tt = 0; tt < 4; tt++)
                #pragma unroll
                for (int r = 0; r < 4; r++) mx = fmaxf(mx, sa[tt][tq][r]);
            mx = fmaxf(mx, __shfl_xor(mx, 16));
            mx = fmaxf(mx, __shfl_xor(mx, 32));
            if (__all(mx - mrun[tq] <= 8.0f)) {
                // deferred: keep old max, P bounded by 2^8, no O rescale
                const float m = mrun[tq];
                float rs = 0.f;
                #pragma unroll
                for (int tt = 0; tt < 4; tt++)
                    #pragma unroll
                    for (int r = 0; r < 4; r++) {
                        float p = __builtin_amdgcn_exp2f(sa[tt][tq][r] - m);
                        sa[tt][tq][r] = p; rs += p;
                    }
                rs += __shfl_xor(rs, 16);
                rs += __shfl_xor(rs, 32);
                lrun[tq] += rs;
            } else {
                float mnew = fmaxf(mrun[tq], mx);
                float al = __builtin_amdgcn_exp2f(mrun[tq] - mnew);
                mrun[tq] = mnew;
                float rs = 0.f;
                #pragma unroll
                for (int tt = 0; tt < 4; tt++)
                    #pragma unroll
                    for (int r = 0; r < 4; r++) {
                        float p = __builtin_amdgcn_exp2f(sa[tt][tq][r] - mnew);
                        sa[tt][tq][r] = p; rs += p;
                    }
                rs += __shfl_xor(rs, 16);
                rs += __shfl_xor(rs, 32);
                lrun[tq] = lrun[tq] * al + rs;
                #pragma unroll
                for (int dt = 0; dt < 4; dt++)
                    #pragma unroll
                    for (int r = 0; r < 4; r++) oacc[tq][dt][r] *= al;
            }
            // P^T -> Ps [q][t]: 4 consecutive t per lane, packed b64
            #pragma unroll
            for (int tt = 0; tt < 4; tt++) {
                uint2 pk;
                pk.x = pack_bf16_hu(sa[tt][tq][0], sa[tt][tq][1]);
                pk.y = pack_bf16_hu(sa[tt][tq][2], sa[tt][tq][3]);
                *(uint2*)&Ps[(w * 32 + tq * 16 + ln) * 72 + tt * 16 + qd * 4] = pk;
            }
        }

        // ---- write V[j+1] transpose into next buffer (overlaps other waves' MFMA) ----
        if (j < 31 && w < 4) {
            U16x8 a, b; a.u = vr0; b.u = vr1;
            #pragma unroll
            for (int e = 0; e < 8; e++) {
                uint32_t pk = (uint32_t)a.s[e] | ((uint32_t)b.s[e] << 16);
                *(uint32_t*)&Vt[nxt][(vsg * 8 + e) * 72 + 2 * vu] = pk;
            }
        }

        // ---- O^T += V^T P^T  (A = V^T from Vt[cur], B = P^T from Ps) ----
        bf16x8 pa[2][2], vb[4][2];
        #pragma unroll
        for (int tq = 0; tq < 2; tq++)
            #pragma unroll
            for (int ks = 0; ks < 2; ks++)
                pa[tq][ks] = *(const bf16x8*)&Ps[(w * 32 + tq * 16 + ln) * 72 + ks * 32 + qd * 8];
        #pragma unroll
        for (int dt = 0; dt < 4; dt++)
            #pragma unroll
            for (int ks = 0; ks < 2; ks++)
                vb[dt][ks] = *(const bf16x8*)&Vt[cur][(dt * 16 + ln) * 72 + ks * 32 + qd * 8];
        __builtin_amdgcn_s_setprio(1);
        #pragma unroll
        for (int tq = 0; tq < 2; tq++)
            #pragma unroll
            for (int dt = 0; dt < 4; dt++)
                #pragma unroll
                for (int ks = 0; ks < 2; ks++)
                    oacc[tq][dt] = __builtin_amdgcn_mfma_f32_16x16x32_bf16(vb[dt][ks], pa[tq][ks], oacc[tq][dt], 0, 0, 0);
        __builtin_amdgcn_s_setprio(0);
    }

    // normalize (inv already in right lane), pack d-consecutive b64 into Ps, then store
    #pragma unroll
    for (int tq = 0; tq < 2; tq++) {
        float inv = 1.0f / lrun[tq];
        #pragma unroll
        for (int dt = 0; dt < 4; dt++) {
            uint2 pk;
            pk.x = pack_bf16_hu(oacc[tq][dt][0] * inv, oacc[tq][dt][1] * inv);
            pk.y = pack_bf16_hu(oacc[tq][dt][2] * inv, oacc[tq][dt][3] * inv);
            *(uint2*)&Ps[(w * 32 + tq * 16 + ln) * 72 + dt * 16 + qd * 4] = pk;
        }
    }
    __syncthreads();
    #pragma unroll
    for (int i = 0; i < 4; i++) {
        int c = tid + i * 512, row = c >> 3, sg = c & 7;
        *(uint4*)&Of[base + (size_t)(q0 + row) * 64 + sg * 8] =
            *(const uint4*)&Ps[row * 72 + sg * 8];
    }
}

// ---------- launch ----------
extern "C" void kernel_launch(void* const* d_in, const int* in_sizes, int n_in,
                              void* d_out, int out_size, void* d_ws, size_t ws_size,
                              hipStream_t stream) {
    const float* q   = (const float*)d_in[0];
    const float* k   = (const float*)d_in[1];
    const float* v   = (const float*)d_in[2];
    const float* w_q = (const float*)d_in[3];
    const float* b_q = (const float*)d_in[4];
    const float* w_k = (const float*)d_in[5];
    const float* b_k = (const float*)d_in[6];
    const float* w_v = (const float*)d_in[7];
    const float* b_v = (const float*)d_in[8];
    const float* w_0 = (const float*)d_in[9];
    const float* b_0 = (const float*)d_in[10];

    uint16_t* ws  = (uint16_t*)d_ws;
    const size_t WE = 1048576, NE = 8388608;
    uint16_t* wtq = ws;
    uint16_t* wtk = wtq + WE;
    uint16_t* wtv = wtk + WE;
    uint16_t* wt0 = wtv + WE;
    uint16_t* xq  = wt0 + WE;
    uint16_t* xk  = xq + NE;
    uint16_t* xv  = xk + NE;
    uint16_t* Qh  = xv + NE;
    uint16_t* Kh  = Qh + NE;
    uint16_t* Vh  = Kh + NE;
    uint16_t* Pf  = xq;              // alias: xq dead after QKV projection

    const dim3 tb(256);
    const dim3 gT(16, 16, 4);
    const dim3 gC(8192, 3);          // fused cast
    const dim3 gQ(8, 64, 3);         // fused QKV GEMM
    const dim3 gO(8, 64);            // output GEMM
    const dim3 gA(8, 64);            // attn: 256-row q tiles
    const int  n4 = 2097152;

    // Q scale folds 1/sqrt(dk) AND log2(e) for exp2-domain softmax
    const float qscale = 0.125f * 1.44269504f;

    transpose_cast4<<<gT, tb, 0, stream>>>(w_q, w_k, w_v, w_0, wtq, wtk, wtv, wt0);
    cast3_f32_bf16<<<gC, tb, 0, stream>>>(q, k, v, xq, xk, xv, n4);
    gemm_qkv<<<gQ, tb, 0, stream>>>(xq, xk, xv, wtq, wtk, wtv, b_q, b_k, b_v,
                                    Qh, Kh, Vh, qscale);
    attn_kernel<<<gA, dim3(512), 0, stream>>>(Qh, Kh, Vh, Pf);
    gemm_o<<<gO, tb, 0, stream>>>(Pf, wt0, b_0, (float*)d_out);
}

// Round 2
// 397.202 us; speedup vs baseline: 1.0654x; 1.0654x over previous
//
#include <hip/hip_runtime.h>
#include <stdint.h>

// ---------- types ----------
typedef __bf16 bf16x8 __attribute__((ext_vector_type(8)));
typedef float  f32x4  __attribute__((ext_vector_type(4)));

union U16x8 { uint4 u; uint16_t s[8]; };

__device__ __forceinline__ uint16_t f2b(float f) {
    union { float f; uint32_t u; } c; c.f = f;
    uint32_t u = c.u;
    uint32_t r = u + 0x7fffu + ((u >> 16) & 1u);   // round-to-nearest-even
    return (uint16_t)(r >> 16);
}

__device__ __forceinline__ uint32_t asu(float f) {
    union { float f; uint32_t u; } c; c.f = f; return c.u;
}
// pack two f32 -> two bf16 (half-up rounding), lo = a, hi = b
__device__ __forceinline__ uint32_t pack_bf16_hu(float a, float b) {
    uint32_t ua = asu(a) + 0x8000u, ub = asu(b) + 0x8000u;
    return (ua >> 16) | (ub & 0xffff0000u);        // v_lshr + v_and_or
}

// async global->LDS, 16B per lane; dest must be lane-contiguous
__device__ __forceinline__ void gl_lds16(const uint16_t* g, uint16_t* l) {
    __builtin_amdgcn_global_load_lds(
        (const __attribute__((address_space(1))) void*)g,
        (__attribute__((address_space(3))) void*)l, 16, 0, 0);
}

// ---------- prep kernels ----------
// q,k,v fp32 -> bf16 in one launch (y selects tensor)
__global__ void cast3_f32_bf16(const float* __restrict__ x0, const float* __restrict__ x1,
                               const float* __restrict__ x2,
                               uint16_t* __restrict__ y0, uint16_t* __restrict__ y1,
                               uint16_t* __restrict__ y2, int n4) {
    const float* x; uint16_t* y;
    switch (blockIdx.y) {
        case 0: x = x0; y = y0; break;
        case 1: x = x1; y = y1; break;
        default: x = x2; y = y2; break;
    }
    int i = blockIdx.x * blockDim.x + threadIdx.x;
    if (i < n4) {
        float4 v = ((const float4*)x)[i];
        ushort4 o;
        o.x = f2b(v.x); o.y = f2b(v.y); o.z = f2b(v.z); o.w = f2b(v.w);
        *(ushort4*)(y + (size_t)i * 4) = o;
    }
}

// 4 weights [1024,1024] fp32 [k][n] -> bf16 [n][k], one launch (z selects weight)
__global__ void transpose_cast4(const float* __restrict__ W0, const float* __restrict__ W1,
                                const float* __restrict__ W2, const float* __restrict__ W3,
                                uint16_t* __restrict__ O0, uint16_t* __restrict__ O1,
                                uint16_t* __restrict__ O2, uint16_t* __restrict__ O3) {
    __shared__ float tile[64][65];
    const float* W; uint16_t* Wt;
    switch (blockIdx.z) {
        case 0: W = W0; Wt = O0; break;
        case 1: W = W1; Wt = O1; break;
        case 2: W = W2; Wt = O2; break;
        default: W = W3; Wt = O3; break;
    }
    const int k0 = blockIdx.y * 64, n0 = blockIdx.x * 64;
    const int tx = threadIdx.x & 63, ty = threadIdx.x >> 6;
    #pragma unroll
    for (int r = ty; r < 64; r += 4)
        tile[r][tx] = W[(size_t)(k0 + r) * 1024 + n0 + tx];
    __syncthreads();
    #pragma unroll
    for (int r = ty; r < 64; r += 4)
        Wt[(size_t)(n0 + r) * 1024 + k0 + tx] = f2b(tile[tx][r]);
}

// ---------- fused QKV projection GEMM ----------
// C[8192,1024] = A[M,K](bf16) * Bt[N,K](bf16) + bias, out bf16 head-split [B,H,S,dk]
// blockIdx.z picks (A, Bt, bias, out); z==0 (Q) applies qscale.
__global__ __launch_bounds__(256, 3)
void gemm_qkv(const uint16_t* __restrict__ A0, const uint16_t* __restrict__ A1,
              const uint16_t* __restrict__ A2,
              const uint16_t* __restrict__ B0, const uint16_t* __restrict__ B1,
              const uint16_t* __restrict__ B2,
              const float* __restrict__ c0, const float* __restrict__ c1,
              const float* __restrict__ c2,
              uint16_t* __restrict__ O0, uint16_t* __restrict__ O1,
              uint16_t* __restrict__ O2, float qscale) {
    __shared__ uint16_t SH[2 * 128 * 32] __attribute__((aligned(16)));
    uint16_t* As = SH;
    uint16_t* Bs = SH + 128 * 32;

    const uint16_t* A; const uint16_t* Bt; const float* bias; uint16_t* Cout; float scale;
    switch (blockIdx.z) {
        case 0: A = A0; Bt = B0; bias = c0; Cout = O0; scale = qscale; break;
        case 1: A = A1; Bt = B1; bias = c1; Cout = O1; scale = 1.0f;  break;
        default: A = A2; Bt = B2; bias = c2; Cout = O2; scale = 1.0f; break;
    }

    const int tid = threadIdx.x;
    const int m0 = blockIdx.y * 128, n0 = blockIdx.x * 128;
    const int l = tid & 63, ln = l & 15, qd = l >> 4;
    const int w = tid >> 6;
    const int wm = (w >> 1) * 64, wn = (w & 1) * 64;

    f32x4 acc[4][4] = {};

    for (int kk = 0; kk < 1024; kk += 32) {
        __syncthreads();
        #pragma unroll
        for (int i = 0; i < 2; i++) {
            int c = tid + i * 256;           // 512 chunks of 8 bf16 per tile
            gl_lds16(&A[(size_t)(m0 + (c >> 2)) * 1024 + kk + (c & 3) * 8], &As[c * 8]);
            gl_lds16(&Bt[(size_t)(n0 + (c >> 2)) * 1024 + kk + (c & 3) * 8], &Bs[c * 8]);
        }
        __syncthreads();

        bf16x8 af[4], bfr[4];
        #pragma unroll
        for (int i = 0; i < 4; i++)
            af[i] = *(const bf16x8*)&As[(wm + i * 16 + ln) * 32 + qd * 8];
        #pragma unroll
        for (int j = 0; j < 4; j++)
            bfr[j] = *(const bf16x8*)&Bs[(wn + j * 16 + ln) * 32 + qd * 8];
        #pragma unroll
        for (int i = 0; i < 4; i++)
            #pragma unroll
            for (int j = 0; j < 4; j++)
                acc[i][j] = __builtin_amdgcn_mfma_f32_16x16x32_bf16(af[i], bfr[j], acc[i][j], 0, 0, 0);
    }

    float bv[4];
    #pragma unroll
    for (int j = 0; j < 4; j++) bv[j] = bias[n0 + wn + j * 16 + ln];

    __syncthreads();
    uint16_t* scr = (uint16_t*)SH + w * 1024;      // per-wave 16x64 bf16 patch
    const int colb = n0 + wn;
    const int h = colb >> 6;
    #pragma unroll
    for (int i = 0; i < 4; i++) {
        #pragma unroll
        for (int j = 0; j < 4; j++)
            #pragma unroll
            for (int r = 0; r < 4; r++)
                scr[(qd * 4 + r) * 64 + j * 16 + ln] = f2b((acc[i][j][r] + bv[j]) * scale);
        #pragma unroll
        for (int ii = 0; ii < 2; ii++) {
            int ch = ii * 64 + l, row = ch >> 3, sg = ch & 7;
            int grow = m0 + wm + i * 16 + row;
            int b = grow >> 11, s = grow & 2047;
            *(uint4*)&Cout[(size_t)((b * 16 + h) * 2048 + s) * 64 + sg * 8] =
                *(uint4*)&scr[row * 64 + sg * 8];
        }
    }
}

// ---------- output projection GEMM (fp32 out) ----------
__global__ __launch_bounds__(256, 3)
void gemm_o(const uint16_t* __restrict__ A, const uint16_t* __restrict__ Bt,
            const float* __restrict__ bias, float* __restrict__ Cout) {
    __shared__ uint16_t SH[2 * 128 * 32] __attribute__((aligned(16)));
    uint16_t* As = SH;
    uint16_t* Bs = SH + 128 * 32;

    const int tid = threadIdx.x;
    const int m0 = blockIdx.y * 128, n0 = blockIdx.x * 128;
    const int l = tid & 63, ln = l & 15, qd = l >> 4;
    const int w = tid >> 6;
    const int wm = (w >> 1) * 64, wn = (w & 1) * 64;

    f32x4 acc[4][4] = {};

    for (int kk = 0; kk < 1024; kk += 32) {
        __syncthreads();
        #pragma unroll
        for (int i = 0; i < 2; i++) {
            int c = tid + i * 256;
            gl_lds16(&A[(size_t)(m0 + (c >> 2)) * 1024 + kk + (c & 3) * 8], &As[c * 8]);
            gl_lds16(&Bt[(size_t)(n0 + (c >> 2)) * 1024 + kk + (c & 3) * 8], &Bs[c * 8]);
        }
        __syncthreads();

        bf16x8 af[4], bfr[4];
        #pragma unroll
        for (int i = 0; i < 4; i++)
            af[i] = *(const bf16x8*)&As[(wm + i * 16 + ln) * 32 + qd * 8];
        #pragma unroll
        for (int j = 0; j < 4; j++)
            bfr[j] = *(const bf16x8*)&Bs[(wn + j * 16 + ln) * 32 + qd * 8];
        #pragma unroll
        for (int i = 0; i < 4; i++)
            #pragma unroll
            for (int j = 0; j < 4; j++)
                acc[i][j] = __builtin_amdgcn_mfma_f32_16x16x32_bf16(af[i], bfr[j], acc[i][j], 0, 0, 0);
    }

    float bv[4];
    #pragma unroll
    for (int j = 0; j < 4; j++) bv[j] = bias[n0 + wn + j * 16 + ln];

    __syncthreads();
    float* scr = (float*)SH + w * 1024;            // per-wave 16x64 f32 patch
    #pragma unroll
    for (int i = 0; i < 4; i++) {
        #pragma unroll
        for (int j = 0; j < 4; j++)
            #pragma unroll
            for (int r = 0; r < 4; r++)
                scr[(qd * 4 + r) * 64 + j * 16 + ln] = acc[i][j][r] + bv[j];
        #pragma unroll
        for (int ii = 0; ii < 4; ii++) {
            int ch = ii * 64 + l, row = ch >> 4, sg = ch & 15;
            *(float4*)&Cout[(size_t)(m0 + wm + i * 16 + row) * 1024 + n0 + wn + sg * 4] =
                *(float4*)&scr[row * 64 + sg * 4];
        }
    }
}

// ---------- flash attention (S^T and O^T formulation) ----------
// Qh holds log2e-scaled Q. 512 threads, 256-row Q tile.
// Double-buffered K/V, ONE barrier per KV tile:
//   K: pre-swizzled global_load_lds into linear [64][64] (chunk c' = c ^ (t&7)),
//      same swizzle on the LDS-read side -> conflict-free b128 reads, zero regs.
//   V: waves 0-3 load + transpose-pack + ds_write into Vt[nxt] IMMEDIATELY in the
//      prefetch section (short register live range -- the round-1 version held the
//      V registers across QK^T+softmax and the compiler spilled them to scratch,
//      +267 MB of HBM write traffic per dispatch). Waves 4-7 run ahead into QK^T.
//   Softmax: defer-max (THR=8 in log2 domain); s_setprio(1) around MFMA clusters.
__global__ __launch_bounds__(512, 4)
void attn_kernel(const uint16_t* __restrict__ Qh, const uint16_t* __restrict__ Kh,
                 const uint16_t* __restrict__ Vh, uint16_t* __restrict__ Of) {
    __shared__ uint16_t Ks[2][64 * 64] __attribute__((aligned(16)));  // [t][d], XOR-chunk-swizzled
    __shared__ uint16_t Vt[2][64 * 72] __attribute__((aligned(16)));  // [d][t], reg-transposed
    __shared__ uint16_t Ps[256 * 72]   __attribute__((aligned(16)));  // [q][t], per-wave 32 rows

    const int tid = threadIdx.x;
    const int w = tid >> 6, l = tid & 63, ln = l & 15, qd = l >> 4;
    const size_t base = (size_t)blockIdx.y * 131072;
    const int q0 = blockIdx.x * 256;

    // K staging geometry (thread-constant): LDS chunk tid <- global chunk c^(t&7)
    const int krow = tid >> 3;                         // 0..63
    const int kchunk = (tid & 7) ^ (krow & 7);         // swizzled source chunk
    // per-lane swizzled read offsets (halfwords) for the two 32-wide k slices
    const int swz0 = ((0 + qd) ^ (ln & 7)) * 8;
    const int swz1 = ((4 + qd) ^ (ln & 7)) * 8;
    // V staging geometry (valid for w < 4)
    const int vu = tid & 31, vsg = tid >> 5;

    // Q fragments (B-operand): [n=q][k=d]
    bf16x8 qf[2][2];
    #pragma unroll
    for (int tq = 0; tq < 2; tq++)
        #pragma unroll
        for (int ks = 0; ks < 2; ks++)
            qf[tq][ks] = *(const bf16x8*)&Qh[base + (size_t)(q0 + w * 32 + tq * 16 + ln) * 64 + ks * 32 + qd * 8];

    f32x4 oacc[2][4] = {};                          // [tq][dt], O^T: row=d, col=q
    float mrun[2] = { -__builtin_inff(), -__builtin_inff() };
    float lrun[2] = { 0.f, 0.f };

    // ---- prologue: stage tile 0 ----
    gl_lds16(&Kh[base + (size_t)krow * 64 + kchunk * 8], &Ks[0][tid * 8]);
    if (w < 4) {
        uint4 vr0 = *(const uint4*)&Vh[base + (size_t)(2 * vu) * 64 + vsg * 8];
        uint4 vr1 = *(const uint4*)&Vh[base + (size_t)(2 * vu + 1) * 64 + vsg * 8];
        U16x8 a, b; a.u = vr0; b.u = vr1;
        #pragma unroll
        for (int e = 0; e < 8; e++) {
            uint32_t pk = (uint32_t)a.s[e] | ((uint32_t)b.s[e] << 16);
            *(uint32_t*)&Vt[0][(vsg * 8 + e) * 72 + 2 * vu] = pk;
        }
    }

    for (int j = 0; j < 32; j++) {
        const int cur = j & 1, nxt = cur ^ 1;
        __syncthreads();   // publishes K/V of tile j; protects buffers of tile j+1

        // ---- prefetch tile j+1 (V staged immediately: short reg live range) ----
        if (j < 31) {
            const int t0n = (j + 1) * 64;
            if (w < 4) {
                uint4 vr0 = *(const uint4*)&Vh[base + (size_t)(t0n + 2 * vu) * 64 + vsg * 8];
                uint4 vr1 = *(const uint4*)&Vh[base + (size_t)(t0n + 2 * vu + 1) * 64 + vsg * 8];
                gl_lds16(&Kh[base + (size_t)(t0n + krow) * 64 + kchunk * 8], &Ks[nxt][tid * 8]);
                U16x8 a, b; a.u = vr0; b.u = vr1;
                #pragma unroll
                for (int e = 0; e < 8; e++) {
                    uint32_t pk = (uint32_t)a.s[e] | ((uint32_t)b.s[e] << 16);
                    *(uint32_t*)&Vt[nxt][(vsg * 8 + e) * 72 + 2 * vu] = pk;
                }
            } else {
                gl_lds16(&Kh[base + (size_t)(t0n + krow) * 64 + kchunk * 8], &Ks[nxt][tid * 8]);
            }
        }

        // ---- S^T = K Q^T : row=t=(qd*4+r), col=q=ln  (log2 domain) ----
        bf16x8 kb[4][2];
        #pragma unroll
        for (int tt = 0; tt < 4; tt++) {
            kb[tt][0] = *(const bf16x8*)&Ks[cur][(tt * 16 + ln) * 64 + swz0];
            kb[tt][1] = *(const bf16x8*)&Ks[cur][(tt * 16 + ln) * 64 + swz1];
        }
        f32x4 sa[4][2] = {};
        __builtin_amdgcn_s_setprio(1);
        #pragma unroll
        for (int tt = 0; tt < 4; tt++)
            #pragma unroll
            for (int tq = 0; tq < 2; tq++)
                #pragma unroll
                for (int ks = 0; ks < 2; ks++)
                    sa[tt][tq] = __builtin_amdgcn_mfma_f32_16x16x32_bf16(kb[tt][ks], qf[tq][ks], sa[tt][tq], 0, 0, 0);
        __builtin_amdgcn_s_setprio(0);

        // ---- online softmax in log2 domain, defer-max rescale skip ----
        #pragma unroll
        for (int tq = 0; tq < 2; tq++) {
            float mx = -__builtin_inff();
            #pragma unroll
            for (int tt = 0; tt < 4; tt++)
                #pragma unroll
                for (int r = 0; r < 4; r++) mx = fmaxf(mx, sa[tt][tq][r]);
            mx = fmaxf(mx, __shfl_xor(mx, 16));
            mx = fmaxf(mx, __shfl_xor(mx, 32));
            if (__all(mx - mrun[tq] <= 8.0f)) {
                // deferred: keep old max, P bounded by 2^8, no O rescale
                const float m = mrun[tq];
                float rs = 0.f;
                #pragma unroll
                for (int tt = 0; tt < 4; tt++)
                    #pragma unroll
                    for (int r = 0; r < 4; r++) {
                        float p = __builtin_amdgcn_exp2f(sa[tt][tq][r] - m);
                        sa[tt][tq][r] = p; rs += p;
                    }
                rs += __shfl_xor(rs, 16);
                rs += __shfl_xor(rs, 32);
                lrun[tq] += rs;
            } else {
                float mnew = fmaxf(mrun[tq], mx);
                float al = __builtin_amdgcn_exp2f(mrun[tq] - mnew);
                mrun[tq] = mnew;
                float rs = 0.f;
                #pragma unroll
                for (int tt = 0; tt < 4; tt++)
                    #pragma unroll
                    for (int r = 0; r < 4; r++) {
                        float p = __builtin_amdgcn_exp2f(sa[tt][tq][r] - mnew);
                        sa[tt][tq][r] = p; rs += p;
                    }
                rs += __shfl_xor(rs, 16);
                rs += __shfl_xor(rs, 32);
                lrun[tq] = lrun[tq] * al + rs;
                #pragma unroll
                for (int dt = 0; dt < 4; dt++)
                    #pragma unroll
                    for (int r = 0; r < 4; r++) oacc[tq][dt][r] *= al;
            }
            // P^T -> Ps [q][t]: 4 consecutive t per lane, packed b64
            #pragma unroll
            for (int tt = 0; tt < 4; tt++) {
                uint2 pk;
                pk.x = pack_bf16_hu(sa[tt][tq][0], sa[tt][tq][1]);
                pk.y = pack_bf16_hu(sa[tt][tq][2], sa[tt][tq][3]);
                *(uint2*)&Ps[(w * 32 + tq * 16 + ln) * 72 + tt * 16 + qd * 4] = pk;
            }
        }

        // ---- O^T += V^T P^T  (A = V^T from Vt[cur], B = P^T from Ps) ----
        bf16x8 pa[2][2], vb[4][2];
        #pragma unroll
        for (int tq = 0; tq < 2; tq++)
            #pragma unroll
            for (int ks = 0; ks < 2; ks++)
                pa[tq][ks] = *(const bf16x8*)&Ps[(w * 32 + tq * 16 + ln) * 72 + ks * 32 + qd * 8];
        #pragma unroll
        for (int dt = 0; dt < 4; dt++)
            #pragma unroll
            for (int ks = 0; ks < 2; ks++)
                vb[dt][ks] = *(const bf16x8*)&Vt[cur][(dt * 16 + ln) * 72 + ks * 32 + qd * 8];
        __builtin_amdgcn_s_setprio(1);
        #pragma unroll
        for (int tq = 0; tq < 2; tq++)
            #pragma unroll
            for (int dt = 0; dt < 4; dt++)
                #pragma unroll
                for (int ks = 0; ks < 2; ks++)
                    oacc[tq][dt] = __builtin_amdgcn_mfma_f32_16x16x32_bf16(vb[dt][ks], pa[tq][ks], oacc[tq][dt], 0, 0, 0);
        __builtin_amdgcn_s_setprio(0);
    }

    // normalize (inv already in right lane), pack d-consecutive b64 into Ps, then store
    #pragma unroll
    for (int tq = 0; tq < 2; tq++) {
        float inv = 1.0f / lrun[tq];
        #pragma unroll
        for (int dt = 0; dt < 4; dt++) {
            uint2 pk;
            pk.x = pack_bf16_hu(oacc[tq][dt][0] * inv, oacc[tq][dt][1] * inv);
            pk.y = pack_bf16_hu(oacc[tq][dt][2] * inv, oacc[tq][dt][3] * inv);
            *(uint2*)&Ps[(w * 32 + tq * 16 + ln) * 72 + dt * 16 + qd * 4] = pk;
        }
    }
    __syncthreads();
    #pragma unroll
    for (int i = 0; i < 4; i++) {
        int c = tid + i * 512, row = c >> 3, sg = c & 7;
        *(uint4*)&Of[base + (size_t)(q0 + row) * 64 + sg * 8] =
            *(const uint4*)&Ps[row * 72 + sg * 8];
    }
}

// ---------- launch ----------
extern "C" void kernel_launch(void* const* d_in, const int* in_sizes, int n_in,
                              void* d_out, int out_size, void* d_ws, size_t ws_size,
                              hipStream_t stream) {
    const float* q   = (const float*)d_in[0];
    const float* k   = (const float*)d_in[1];
    const float* v   = (const float*)d_in[2];
    const float* w_q = (const float*)d_in[3];
    const float* b_q = (const float*)d_in[4];
    const float* w_k = (const float*)d_in[5];
    const float* b_k = (const float*)d_in[6];
    const float* w_v = (const float*)d_in[7];
    const float* b_v = (const float*)d_in[8];
    const float* w_0 = (const float*)d_in[9];
    const float* b_0 = (const float*)d_in[10];

    uint16_t* ws  = (uint16_t*)d_ws;
    const size_t WE = 1048576, NE = 8388608;
    uint16_t* wtq = ws;
    uint16_t* wtk = wtq + WE;
    uint16_t* wtv = wtk + WE;
    uint16_t* wt0 = wtv + WE;
    uint16_t* xq  = wt0 + WE;
    uint16_t* xk  = xq + NE;
    uint16_t* xv  = xk + NE;
    uint16_t* Qh  = xv + NE;
    uint16_t* Kh  = Qh + NE;
    uint16_t* Vh  = Kh + NE;
    uint16_t* Pf  = xq;              // alias: xq dead after QKV projection

    const dim3 tb(256);
    const dim3 gT(16, 16, 4);
    const dim3 gC(8192, 3);          // fused cast
    const dim3 gQ(8, 64, 3);         // fused QKV GEMM
    const dim3 gO(8, 64);            // output GEMM
    const dim3 gA(8, 64);            // attn: 256-row q tiles
    const int  n4 = 2097152;

    // Q scale folds 1/sqrt(dk) AND log2(e) for exp2-domain softmax
    const float qscale = 0.125f * 1.44269504f;

    transpose_cast4<<<gT, tb, 0, stream>>>(w_q, w_k, w_v, w_0, wtq, wtk, wtv, wt0);
    cast3_f32_bf16<<<gC, tb, 0, stream>>>(q, k, v, xq, xk, xv, n4);
    gemm_qkv<<<gQ, tb, 0, stream>>>(xq, xk, xv, wtq, wtk, wtv, b_q, b_k, b_v,
                                    Qh, Kh, Vh, qscale);
    attn_kernel<<<gA, dim3(512), 0, stream>>>(Qh, Kh, Vh, Pf);
    gemm_o<<<gO, tb, 0, stream>>>(Pf, wt0, b_0, (float*)d_out);
}

// Round 4
// 381.370 us; speedup vs baseline: 1.1096x; 1.0415x over previous
//
#include <hip/hip_runtime.h>
#include <stdint.h>

// ---------- types ----------
typedef __bf16 bf16x8 __attribute__((ext_vector_type(8)));
typedef float  f32x4  __attribute__((ext_vector_type(4)));

union U16x8 { uint4 u; uint16_t s[8]; };

__device__ __forceinline__ uint16_t f2b(float f) {
    union { float f; uint32_t u; } c; c.f = f;
    uint32_t u = c.u;
    uint32_t r = u + 0x7fffu + ((u >> 16) & 1u);   // round-to-nearest-even
    return (uint16_t)(r >> 16);
}

__device__ __forceinline__ uint32_t asu(float f) {
    union { float f; uint32_t u; } c; c.f = f; return c.u;
}
// pack two f32 -> two bf16 (half-up rounding), lo = a, hi = b
__device__ __forceinline__ uint32_t pack_bf16_hu(float a, float b) {
    uint32_t ua = asu(a) + 0x8000u, ub = asu(b) + 0x8000u;
    return (ua >> 16) | (ub & 0xffff0000u);        // v_lshr + v_and_or
}

// async global->LDS, 16B per lane; dest must be lane-contiguous
__device__ __forceinline__ void gl_lds16(const uint16_t* g, uint16_t* l) {
    __builtin_amdgcn_global_load_lds(
        (const __attribute__((address_space(1))) void*)g,
        (__attribute__((address_space(3))) void*)l, 16, 0, 0);
}

// ---------- prep kernels ----------
// q,k,v fp32 -> bf16 in one launch (y selects tensor)
__global__ void cast3_f32_bf16(const float* __restrict__ x0, const float* __restrict__ x1,
                               const float* __restrict__ x2,
                               uint16_t* __restrict__ y0, uint16_t* __restrict__ y1,
                               uint16_t* __restrict__ y2, int n4) {
    const float* x; uint16_t* y;
    switch (blockIdx.y) {
        case 0: x = x0; y = y0; break;
        case 1: x = x1; y = y1; break;
        default: x = x2; y = y2; break;
    }
    int i = blockIdx.x * blockDim.x + threadIdx.x;
    if (i < n4) {
        float4 v = ((const float4*)x)[i];
        ushort4 o;
        o.x = f2b(v.x); o.y = f2b(v.y); o.z = f2b(v.z); o.w = f2b(v.w);
        *(ushort4*)(y + (size_t)i * 4) = o;
    }
}

// 4 weights [1024,1024] fp32 [k][n] -> bf16 [n][k], one launch (z selects weight)
__global__ void transpose_cast4(const float* __restrict__ W0, const float* __restrict__ W1,
                                const float* __restrict__ W2, const float* __restrict__ W3,
                                uint16_t* __restrict__ O0, uint16_t* __restrict__ O1,
                                uint16_t* __restrict__ O2, uint16_t* __restrict__ O3) {
    __shared__ float tile[64][65];
    const float* W; uint16_t* Wt;
    switch (blockIdx.z) {
        case 0: W = W0; Wt = O0; break;
        case 1: W = W1; Wt = O1; break;
        case 2: W = W2; Wt = O2; break;
        default: W = W3; Wt = O3; break;
    }
    const int k0 = blockIdx.y * 64, n0 = blockIdx.x * 64;
    const int tx = threadIdx.x & 63, ty = threadIdx.x >> 6;
    #pragma unroll
    for (int r = ty; r < 64; r += 4)
        tile[r][tx] = W[(size_t)(k0 + r) * 1024 + n0 + tx];
    __syncthreads();
    #pragma unroll
    for (int r = ty; r < 64; r += 4)
        Wt[(size_t)(n0 + r) * 1024 + k0 + tx] = f2b(tile[tx][r]);
}

// ---------- fused QKV projection GEMM ----------
// C[8192,1024] = A[M,K](bf16) * Bt[N,K](bf16) + bias, out bf16 head-split [B,H,S,dk]
// blockIdx.z picks (A, Bt, bias, out); z==0 (Q) applies qscale.
__global__ __launch_bounds__(256, 3)
void gemm_qkv(const uint16_t* __restrict__ A0, const uint16_t* __restrict__ A1,
              const uint16_t* __restrict__ A2,
              const uint16_t* __restrict__ B0, const uint16_t* __restrict__ B1,
              const uint16_t* __restrict__ B2,
              const float* __restrict__ c0, const float* __restrict__ c1,
              const float* __restrict__ c2,
              uint16_t* __restrict__ O0, uint16_t* __restrict__ O1,
              uint16_t* __restrict__ O2, float qscale) {
    __shared__ uint16_t SH[2 * 128 * 32] __attribute__((aligned(16)));
    uint16_t* As = SH;
    uint16_t* Bs = SH + 128 * 32;

    const uint16_t* A; const uint16_t* Bt; const float* bias; uint16_t* Cout; float scale;
    switch (blockIdx.z) {
        case 0: A = A0; Bt = B0; bias = c0; Cout = O0; scale = qscale; break;
        case 1: A = A1; Bt = B1; bias = c1; Cout = O1; scale = 1.0f;  break;
        default: A = A2; Bt = B2; bias = c2; Cout = O2; scale = 1.0f; break;
    }

    const int tid = threadIdx.x;
    const int m0 = blockIdx.y * 128, n0 = blockIdx.x * 128;
    const int l = tid & 63, ln = l & 15, qd = l >> 4;
    const int w = tid >> 6;
    const int wm = (w >> 1) * 64, wn = (w & 1) * 64;

    f32x4 acc[4][4] = {};

    for (int kk = 0; kk < 1024; kk += 32) {
        __syncthreads();
        #pragma unroll
        for (int i = 0; i < 2; i++) {
            int c = tid + i * 256;           // 512 chunks of 8 bf16 per tile
            gl_lds16(&A[(size_t)(m0 + (c >> 2)) * 1024 + kk + (c & 3) * 8], &As[c * 8]);
            gl_lds16(&Bt[(size_t)(n0 + (c >> 2)) * 1024 + kk + (c & 3) * 8], &Bs[c * 8]);
        }
        __syncthreads();

        bf16x8 af[4], bfr[4];
        #pragma unroll
        for (int i = 0; i < 4; i++)
            af[i] = *(const bf16x8*)&As[(wm + i * 16 + ln) * 32 + qd * 8];
        #pragma unroll
        for (int j = 0; j < 4; j++)
            bfr[j] = *(const bf16x8*)&Bs[(wn + j * 16 + ln) * 32 + qd * 8];
        #pragma unroll
        for (int i = 0; i < 4; i++)
            #pragma unroll
            for (int j = 0; j < 4; j++)
                acc[i][j] = __builtin_amdgcn_mfma_f32_16x16x32_bf16(af[i], bfr[j], acc[i][j], 0, 0, 0);
    }

    float bv[4];
    #pragma unroll
    for (int j = 0; j < 4; j++) bv[j] = bias[n0 + wn + j * 16 + ln];

    __syncthreads();
    uint16_t* scr = (uint16_t*)SH + w * 1024;      // per-wave 16x64 bf16 patch
    const int colb = n0 + wn;
    const int h = colb >> 6;
    #pragma unroll
    for (int i = 0; i < 4; i++) {
        #pragma unroll
        for (int j = 0; j < 4; j++)
            #pragma unroll
            for (int r = 0; r < 4; r++)
                scr[(qd * 4 + r) * 64 + j * 16 + ln] = f2b((acc[i][j][r] + bv[j]) * scale);
        #pragma unroll
        for (int ii = 0; ii < 2; ii++) {
            int ch = ii * 64 + l, row = ch >> 3, sg = ch & 7;
            int grow = m0 + wm + i * 16 + row;
            int b = grow >> 11, s = grow & 2047;
            *(uint4*)&Cout[(size_t)((b * 16 + h) * 2048 + s) * 64 + sg * 8] =
                *(uint4*)&scr[row * 64 + sg * 8];
        }
    }
}

// ---------- output projection GEMM (fp32 out) ----------
__global__ __launch_bounds__(256, 3)
void gemm_o(const uint16_t* __restrict__ A, const uint16_t* __restrict__ Bt,
            const float* __restrict__ bias, float* __restrict__ Cout) {
    __shared__ uint16_t SH[2 * 128 * 32] __attribute__((aligned(16)));
    uint16_t* As = SH;
    uint16_t* Bs = SH + 128 * 32;

    const int tid = threadIdx.x;
    const int m0 = blockIdx.y * 128, n0 = blockIdx.x * 128;
    const int l = tid & 63, ln = l & 15, qd = l >> 4;
    const int w = tid >> 6;
    const int wm = (w >> 1) * 64, wn = (w & 1) * 64;

    f32x4 acc[4][4] = {};

    for (int kk = 0; kk < 1024; kk += 32) {
        __syncthreads();
        #pragma unroll
        for (int i = 0; i < 2; i++) {
            int c = tid + i * 256;
            gl_lds16(&A[(size_t)(m0 + (c >> 2)) * 1024 + kk + (c & 3) * 8], &As[c * 8]);
            gl_lds16(&Bt[(size_t)(n0 + (c >> 2)) * 1024 + kk + (c & 3) * 8], &Bs[c * 8]);
        }
        __syncthreads();

        bf16x8 af[4], bfr[4];
        #pragma unroll
        for (int i = 0; i < 4; i++)
            af[i] = *(const bf16x8*)&As[(wm + i * 16 + ln) * 32 + qd * 8];
        #pragma unroll
        for (int j = 0; j < 4; j++)
            bfr[j] = *(const bf16x8*)&Bs[(wn + j * 16 + ln) * 32 + qd * 8];
        #pragma unroll
        for (int i = 0; i < 4; i++)
            #pragma unroll
            for (int j = 0; j < 4; j++)
                acc[i][j] = __builtin_amdgcn_mfma_f32_16x16x32_bf16(af[i], bfr[j], acc[i][j], 0, 0, 0);
    }

    float bv[4];
    #pragma unroll
    for (int j = 0; j < 4; j++) bv[j] = bias[n0 + wn + j * 16 + ln];

    __syncthreads();
    float* scr = (float*)SH + w * 1024;            // per-wave 16x64 f32 patch
    #pragma unroll
    for (int i = 0; i < 4; i++) {
        #pragma unroll
        for (int j = 0; j < 4; j++)
            #pragma unroll
            for (int r = 0; r < 4; r++)
                scr[(qd * 4 + r) * 64 + j * 16 + ln] = acc[i][j][r] + bv[j];
        #pragma unroll
        for (int ii = 0; ii < 4; ii++) {
            int ch = ii * 64 + l, row = ch >> 4, sg = ch & 15;
            *(float4*)&Cout[(size_t)(m0 + wm + i * 16 + row) * 1024 + n0 + wn + sg * 4] =
                *(float4*)&scr[row * 64 + sg * 4];
        }
    }
}

// ---------- flash attention (S^T and O^T formulation) ----------
// Qh holds log2e-scaled Q. 512 threads, 256-row Q tile.
// Double-buffered K/V, ONE barrier per KV tile.
//   K: pre-swizzled global_load_lds into linear [64][64]; same XOR on read side.
//   V: waves 0-3 load+transpose-pack+write into Vt[nxt] immediately (short live range).
// Round 4: round-2-proven softmax semantics (VALU lrun, pack_bf16_hu). The round-3
// MFMA-row-sum + v_cvt_pk experiment failed correctness (absmax 8.6e3) and is
// reverted pending isolation. Kept from round 3 (algebraically neutral):
//   - balanced max tree, merged defer-branch
//   - kb loaded per-tt, vb per-dt-half: ~30 fewer live arch VGPRs in the hot
//     sections, targeting the residual scratch spill (round-2 WRITE_SIZE 26.6 MB
//     vs 16.4 MB legitimate).
__global__ __launch_bounds__(512, 4)
void attn_kernel(const uint16_t* __restrict__ Qh, const uint16_t* __restrict__ Kh,
                 const uint16_t* __restrict__ Vh, uint16_t* __restrict__ Of) {
    __shared__ uint16_t Ks[2][64 * 64] __attribute__((aligned(16)));  // [t][d], XOR-chunk-swizzled
    __shared__ uint16_t Vt[2][64 * 72] __attribute__((aligned(16)));  // [d][t], reg-transposed
    __shared__ uint16_t Ps[256 * 72]   __attribute__((aligned(16)));  // [q][t], per-wave 32 rows

    const int tid = threadIdx.x;
    const int w = tid >> 6, l = tid & 63, ln = l & 15, qd = l >> 4;
    const size_t base = (size_t)blockIdx.y * 131072;
    const int q0 = blockIdx.x * 256;

    // K staging geometry (thread-constant): LDS chunk tid <- global chunk c^(t&7)
    const int krow = tid >> 3;                         // 0..63
    const int kchunk = (tid & 7) ^ (krow & 7);         // swizzled source chunk
    // per-lane swizzled read offsets (halfwords) for the two 32-wide k slices
    const int swz0 = ((0 + qd) ^ (ln & 7)) * 8;
    const int swz1 = ((4 + qd) ^ (ln & 7)) * 8;
    // V staging geometry (valid for w < 4)
    const int vu = tid & 31, vsg = tid >> 5;

    // Q fragments (B-operand): [n=q][k=d]
    bf16x8 qf[2][2];
    #pragma unroll
    for (int tq = 0; tq < 2; tq++)
        #pragma unroll
        for (int ks = 0; ks < 2; ks++)
            qf[tq][ks] = *(const bf16x8*)&Qh[base + (size_t)(q0 + w * 32 + tq * 16 + ln) * 64 + ks * 32 + qd * 8];

    f32x4 oacc[2][4] = {};                          // [tq][dt], O^T: row=d, col=q
    float mrun[2] = { -__builtin_inff(), -__builtin_inff() };
    float lrun[2] = { 0.f, 0.f };

    // ---- prologue: stage tile 0 ----
    gl_lds16(&Kh[base + (size_t)krow * 64 + kchunk * 8], &Ks[0][tid * 8]);
    if (w < 4) {
        uint4 vr0 = *(const uint4*)&Vh[base + (size_t)(2 * vu) * 64 + vsg * 8];
        uint4 vr1 = *(const uint4*)&Vh[base + (size_t)(2 * vu + 1) * 64 + vsg * 8];
        U16x8 a, b; a.u = vr0; b.u = vr1;
        #pragma unroll
        for (int e = 0; e < 8; e++) {
            uint32_t pk = (uint32_t)a.s[e] | ((uint32_t)b.s[e] << 16);
            *(uint32_t*)&Vt[0][(vsg * 8 + e) * 72 + 2 * vu] = pk;
        }
    }

    for (int j = 0; j < 32; j++) {
        const int cur = j & 1, nxt = cur ^ 1;
        __syncthreads();   // publishes K/V of tile j; protects buffers of tile j+1

        // ---- prefetch tile j+1 (V staged immediately: short reg live range) ----
        if (j < 31) {
            const int t0n = (j + 1) * 64;
            if (w < 4) {
                uint4 vr0 = *(const uint4*)&Vh[base + (size_t)(t0n + 2 * vu) * 64 + vsg * 8];
                uint4 vr1 = *(const uint4*)&Vh[base + (size_t)(t0n + 2 * vu + 1) * 64 + vsg * 8];
                gl_lds16(&Kh[base + (size_t)(t0n + krow) * 64 + kchunk * 8], &Ks[nxt][tid * 8]);
                U16x8 a, b; a.u = vr0; b.u = vr1;
                #pragma unroll
                for (int e = 0; e < 8; e++) {
                    uint32_t pk = (uint32_t)a.s[e] | ((uint32_t)b.s[e] << 16);
                    *(uint32_t*)&Vt[nxt][(vsg * 8 + e) * 72 + 2 * vu] = pk;
                }
            } else {
                gl_lds16(&Kh[base + (size_t)(t0n + krow) * 64 + kchunk * 8], &Ks[nxt][tid * 8]);
            }
        }

        // ---- S^T = K Q^T : row=t=(qd*4+r), col=q=ln  (log2 domain) ----
        f32x4 sa[4][2] = {};
        __builtin_amdgcn_s_setprio(1);
        #pragma unroll
        for (int tt = 0; tt < 4; tt++) {
            bf16x8 kb0 = *(const bf16x8*)&Ks[cur][(tt * 16 + ln) * 64 + swz0];
            bf16x8 kb1 = *(const bf16x8*)&Ks[cur][(tt * 16 + ln) * 64 + swz1];
            #pragma unroll
            for (int tq = 0; tq < 2; tq++) {
                sa[tt][tq] = __builtin_amdgcn_mfma_f32_16x16x32_bf16(kb0, qf[tq][0], sa[tt][tq], 0, 0, 0);
                sa[tt][tq] = __builtin_amdgcn_mfma_f32_16x16x32_bf16(kb1, qf[tq][1], sa[tt][tq], 0, 0, 0);
            }
        }
        __builtin_amdgcn_s_setprio(0);

        // ---- online softmax in log2 domain, defer-max rescale skip ----
        #pragma unroll
        for (int tq = 0; tq < 2; tq++) {
            // balanced max tree (fusable to v_max3)
            float a0 = fmaxf(fmaxf(sa[0][tq][0], sa[0][tq][1]), fmaxf(sa[0][tq][2], sa[0][tq][3]));
            float a1 = fmaxf(fmaxf(sa[1][tq][0], sa[1][tq][1]), fmaxf(sa[1][tq][2], sa[1][tq][3]));
            float a2 = fmaxf(fmaxf(sa[2][tq][0], sa[2][tq][1]), fmaxf(sa[2][tq][2], sa[2][tq][3]));
            float a3 = fmaxf(fmaxf(sa[3][tq][0], sa[3][tq][1]), fmaxf(sa[3][tq][2], sa[3][tq][3]));
            float mx = fmaxf(fmaxf(a0, a1), fmaxf(a2, a3));
            mx = fmaxf(mx, __shfl_xor(mx, 16));
            mx = fmaxf(mx, __shfl_xor(mx, 32));
            if (!__all(mx - mrun[tq] <= 8.0f)) {
                float mnew = fmaxf(mrun[tq], mx);
                float al = __builtin_amdgcn_exp2f(mrun[tq] - mnew);
                mrun[tq] = mnew;
                lrun[tq] *= al;
                #pragma unroll
                for (int dt = 0; dt < 4; dt++)
                    #pragma unroll
                    for (int r = 0; r < 4; r++) oacc[tq][dt][r] *= al;
            }
            const float m = mrun[tq];
            float rs = 0.f;
            #pragma unroll
            for (int tt = 0; tt < 4; tt++) {
                float p0 = __builtin_amdgcn_exp2f(sa[tt][tq][0] - m);
                float p1 = __builtin_amdgcn_exp2f(sa[tt][tq][1] - m);
                float p2 = __builtin_amdgcn_exp2f(sa[tt][tq][2] - m);
                float p3 = __builtin_amdgcn_exp2f(sa[tt][tq][3] - m);
                rs += (p0 + p1) + (p2 + p3);
                uint2 pk;
                pk.x = pack_bf16_hu(p0, p1);
                pk.y = pack_bf16_hu(p2, p3);
                *(uint2*)&Ps[(w * 32 + tq * 16 + ln) * 72 + tt * 16 + qd * 4] = pk;
            }
            rs += __shfl_xor(rs, 16);
            rs += __shfl_xor(rs, 32);
            lrun[tq] += rs;
        }

        // ---- O^T += V^T P^T  (A = V^T from Vt[cur], B = P^T from Ps) ----
        bf16x8 pa[2][2];
        #pragma unroll
        for (int tq = 0; tq < 2; tq++)
            #pragma unroll
            for (int ks = 0; ks < 2; ks++)
                pa[tq][ks] = *(const bf16x8*)&Ps[(w * 32 + tq * 16 + ln) * 72 + ks * 32 + qd * 8];
        __builtin_amdgcn_s_setprio(1);
        #pragma unroll
        for (int dtp = 0; dtp < 2; dtp++) {
            bf16x8 vb[2][2];
            #pragma unroll
            for (int dh = 0; dh < 2; dh++)
                #pragma unroll
                for (int ks = 0; ks < 2; ks++)
                    vb[dh][ks] = *(const bf16x8*)&Vt[cur][((dtp * 2 + dh) * 16 + ln) * 72 + ks * 32 + qd * 8];
            #pragma unroll
            for (int tq = 0; tq < 2; tq++)
                #pragma unroll
                for (int dh = 0; dh < 2; dh++)
                    #pragma unroll
                    for (int ks = 0; ks < 2; ks++)
                        oacc[tq][dtp * 2 + dh] = __builtin_amdgcn_mfma_f32_16x16x32_bf16(
                            vb[dh][ks], pa[tq][ks], oacc[tq][dtp * 2 + dh], 0, 0, 0);
        }
        __builtin_amdgcn_s_setprio(0);
    }

    // normalize (inv already in right lane), pack d-consecutive b64 into Ps, then store
    #pragma unroll
    for (int tq = 0; tq < 2; tq++) {
        float inv = 1.0f / lrun[tq];
        #pragma unroll
        for (int dt = 0; dt < 4; dt++) {
            uint2 pk;
            pk.x = pack_bf16_hu(oacc[tq][dt][0] * inv, oacc[tq][dt][1] * inv);
            pk.y = pack_bf16_hu(oacc[tq][dt][2] * inv, oacc[tq][dt][3] * inv);
            *(uint2*)&Ps[(w * 32 + tq * 16 + ln) * 72 + dt * 16 + qd * 4] = pk;
        }
    }
    __syncthreads();
    #pragma unroll
    for (int i = 0; i < 4; i++) {
        int c = tid + i * 512, row = c >> 3, sg = c & 7;
        *(uint4*)&Of[base + (size_t)(q0 + row) * 64 + sg * 8] =
            *(const uint4*)&Ps[row * 72 + sg * 8];
    }
}

// ---------- launch ----------
extern "C" void kernel_launch(void* const* d_in, const int* in_sizes, int n_in,
                              void* d_out, int out_size, void* d_ws, size_t ws_size,
                              hipStream_t stream) {
    const float* q   = (const float*)d_in[0];
    const float* k   = (const float*)d_in[1];
    const float* v   = (const float*)d_in[2];
    const float* w_q = (const float*)d_in[3];
    const float* b_q = (const float*)d_in[4];
    const float* w_k = (const float*)d_in[5];
    const float* b_k = (const float*)d_in[6];
    const float* w_v = (const float*)d_in[7];
    const float* b_v = (const float*)d_in[8];
    const float* w_0 = (const float*)d_in[9];
    const float* b_0 = (const float*)d_in[10];

    uint16_t* ws  = (uint16_t*)d_ws;
    const size_t WE = 1048576, NE = 8388608;
    uint16_t* wtq = ws;
    uint16_t* wtk = wtq + WE;
    uint16_t* wtv = wtk + WE;
    uint16_t* wt0 = wtv + WE;
    uint16_t* xq  = wt0 + WE;
    uint16_t* xk  = xq + NE;
    uint16_t* xv  = xk + NE;
    uint16_t* Qh  = xv + NE;
    uint16_t* Kh  = Qh + NE;
    uint16_t* Vh  = Kh + NE;
    uint16_t* Pf  = xq;              // alias: xq dead after QKV projection

    const dim3 tb(256);
    const dim3 gT(16, 16, 4);
    const dim3 gC(8192, 3);          // fused cast
    const dim3 gQ(8, 64, 3);         // fused QKV GEMM
    const dim3 gO(8, 64);            // output GEMM
    const dim3 gA(8, 64);            // attn: 256-row q tiles
    const int  n4 = 2097152;

    // Q scale folds 1/sqrt(dk) AND log2(e) for exp2-domain softmax
    const float qscale = 0.125f * 1.44269504f;

    transpose_cast4<<<gT, tb, 0, stream>>>(w_q, w_k, w_v, w_0, wtq, wtk, wtv, wt0);
    cast3_f32_bf16<<<gC, tb, 0, stream>>>(q, k, v, xq, xk, xv, n4);
    gemm_qkv<<<gQ, tb, 0, stream>>>(xq, xk, xv, wtq, wtk, wtv, b_q, b_k, b_v,
                                    Qh, Kh, Vh, qscale);
    attn_kernel<<<gA, dim3(512), 0, stream>>>(Qh, Kh, Vh, Pf);
    gemm_o<<<gO, tb, 0, stream>>>(Pf, wt0, b_0, (float*)d_out);
}